// Round 2
// baseline (1997.546 us; speedup 1.0000x reference)
//
#include <hip/hip_runtime.h>
#include <hip/hip_bf16.h>
#include <math.h>

#define B_   8
#define T_   2048
#define DIN  1024
#define H_   1024
#define G_   16
#define M_   (B_ * T_)   // 16384

typedef __hip_bfloat16 bf16;
struct __align__(8) bf4 { bf16 x, y, z, w; };

__device__ __forceinline__ float log_g_dev(float x) {
    // x>=0 : log(x+0.5) ; x<0 : -softplus(-x) = x - log1p(exp(x))
    return (x >= 0.f) ? logf(x + 0.5f) : (x - log1pf(expf(x)));
}

// ---------------------------------------------------------------------------
// GEMM + fused pointwise epilogue.
//   k = x@Wz^T + bz ; q = x@Wh^T + bh
//   t   = log1p(exp(-|k|))
//   lz  = min(k,0) - t          (= -softplus(-k))
//   lc0 = -max(k,0) - t         (= -softplus(k))   -> Cbuf (fp32, d_ws)
//   lv  = lz + log_g(q)                            -> Vbuf (bf16, d_out)
// 64x64 tile, BK=16, 256 threads, 4x4 microtile, X tile shared between Wz/Wh.
// ---------------------------------------------------------------------------
#define BM 64
#define BN 64
#define BK 16

__global__ __launch_bounds__(256) void gemm_kq(
    const float* __restrict__ X,
    const float* __restrict__ Wz, const float* __restrict__ bz,
    const float* __restrict__ Wh, const float* __restrict__ bh,
    float* __restrict__ Cbuf, bf16* __restrict__ Vbuf)
{
    __shared__ float sX[BK][BM];
    __shared__ float sZ[BK][BN];
    __shared__ float sH[BK][BN];

    const int tid  = threadIdx.x;
    const int m0   = blockIdx.x * BM;
    const int n0   = blockIdx.y * BN;
    const int tx   = tid & 15;        // col group (4 cols each)
    const int ty   = tid >> 4;        // row group (4 rows each)
    const int lrow = tid >> 2;        // 0..63 staging row
    const int lk   = (tid & 3) << 2;  // 0,4,8,12 staging k offset

    const float* Xp = X  + (size_t)(m0 + lrow) * DIN + lk;
    const float* Zp = Wz + (size_t)(n0 + lrow) * DIN + lk;
    const float* Hp = Wh + (size_t)(n0 + lrow) * DIN + lk;

    float az[4][4] = {{0.f}}, ah[4][4] = {{0.f}};

    for (int k0 = 0; k0 < DIN; k0 += BK) {
        float4 xv = *(const float4*)(Xp + k0);
        float4 zv = *(const float4*)(Zp + k0);
        float4 hv = *(const float4*)(Hp + k0);
        __syncthreads();
        sX[lk+0][lrow] = xv.x; sX[lk+1][lrow] = xv.y; sX[lk+2][lrow] = xv.z; sX[lk+3][lrow] = xv.w;
        sZ[lk+0][lrow] = zv.x; sZ[lk+1][lrow] = zv.y; sZ[lk+2][lrow] = zv.z; sZ[lk+3][lrow] = zv.w;
        sH[lk+0][lrow] = hv.x; sH[lk+1][lrow] = hv.y; sH[lk+2][lrow] = hv.z; sH[lk+3][lrow] = hv.w;
        __syncthreads();
        #pragma unroll
        for (int kk = 0; kk < BK; ++kk) {
            float4 a   = *(float4*)(&sX[kk][ty << 2]);
            float4 bz4 = *(float4*)(&sZ[kk][tx << 2]);
            float4 bh4 = *(float4*)(&sH[kk][tx << 2]);
            float av[4]  = {a.x, a.y, a.z, a.w};
            float bzv[4] = {bz4.x, bz4.y, bz4.z, bz4.w};
            float bhv[4] = {bh4.x, bh4.y, bh4.z, bh4.w};
            #pragma unroll
            for (int i = 0; i < 4; ++i)
                #pragma unroll
                for (int j = 0; j < 4; ++j) {
                    az[i][j] = fmaf(av[i], bzv[j], az[i][j]);
                    ah[i][j] = fmaf(av[i], bhv[j], ah[i][j]);
                }
        }
    }

    const float4 bzb = *(const float4*)(bz + n0 + (tx << 2));
    const float4 bhb = *(const float4*)(bh + n0 + (tx << 2));
    const float bzv[4] = {bzb.x, bzb.y, bzb.z, bzb.w};
    const float bhv[4] = {bhb.x, bhb.y, bhb.z, bhb.w};

    #pragma unroll
    for (int i = 0; i < 4; ++i) {
        size_t off = (size_t)(m0 + (ty << 2) + i) * H_ + n0 + (tx << 2);
        float c4[4]; bf4 v4;
        bf16* vp = &v4.x;
        #pragma unroll
        for (int j = 0; j < 4; ++j) {
            float k = az[i][j] + bzv[j];
            float q = ah[i][j] + bhv[j];
            float t   = log1pf(expf(-fabsf(k)));
            float lz  = fminf(k, 0.f) - t;
            float lc0 = -fmaxf(k, 0.f) - t;
            c4[j]  = lc0;
            vp[j]  = __float2bfloat16(lz + log_g_dev(q));
        }
        *(float4*)(Cbuf + off) = *(float4*)c4;
        *(bf4*)(Vbuf + off)    = v4;
    }
}

// ---------------------------------------------------------------------------
// Group-norm over C only. One block per (b,t) row of 1024 channels.
//   per group g (64 ch): nrm = ||lc0_g||2 ; fac = (nrm - lse(norms)) / nrm
//   C = lc0 * fac
// ---------------------------------------------------------------------------
__global__ __launch_bounds__(256) void groupnorm_c(float* __restrict__ Cbuf)
{
    __shared__ float snorm[G_];
    __shared__ float s_lse;

    const int row = blockIdx.x;           // b*T + t
    const int tid = threadIdx.x;          // 4 channels each
    const size_t base = (size_t)row * H_ + (tid << 2);

    float4 c4 = *(float4*)(Cbuf + base);
    float cc[4] = {c4.x, c4.y, c4.z, c4.w};

    float ss = cc[0]*cc[0] + cc[1]*cc[1] + cc[2]*cc[2] + cc[3]*cc[3];
    // 16 threads (64 channels) per group; butterfly within 16-lane segment
    ss += __shfl_xor(ss, 1);
    ss += __shfl_xor(ss, 2);
    ss += __shfl_xor(ss, 4);
    ss += __shfl_xor(ss, 8);
    const float nrm = sqrtf(ss);
    if ((tid & 15) == 0) snorm[tid >> 4] = nrm;
    __syncthreads();
    if (tid == 0) {
        float mx = snorm[0];
        #pragma unroll
        for (int g = 1; g < G_; ++g) mx = fmaxf(mx, snorm[g]);
        float se = 0.f;
        #pragma unroll
        for (int g = 0; g < G_; ++g) se += expf(snorm[g] - mx);
        s_lse = mx + logf(se);
    }
    __syncthreads();
    const float fac = (nrm - s_lse) / nrm;

    float4 o = {cc[0]*fac, cc[1]*fac, cc[2]*fac, cc[3]*fac};
    *(float4*)(Cbuf + base) = o;
}

// ---------------------------------------------------------------------------
// Sequential log-space scan over T per (b,h) channel.
//   s_0 = log_g(h0) ; s_t = logaddexp(s_{t-1} + c_t, v_t)
//   out_t = exp(min(s_t, 88))  (clamped finite -> never inf/nan in d_out)
// Vbuf (bf16) aliases Out: each element read before overwritten, same thread.
// ---------------------------------------------------------------------------
__global__ __launch_bounds__(256) void scan_seq(
    const float* __restrict__ Cbuf, bf16* Vbuf /* == Out */,
    const float* __restrict__ h0)
{
    const int ch = blockIdx.x * 256 + threadIdx.x;  // 0..8191
    const int b  = ch >> 10;
    const int h  = ch & 1023;

    float s = log_g_dev(h0[ch]);

    size_t idx = (size_t)b * (T_ * H_) + h;
    float c = Cbuf[idx];
    float v = __bfloat162float(Vbuf[idx]);
    for (int t = 0; t < T_; ++t) {
        size_t nidx = (t == T_ - 1) ? idx : idx + H_;
        float cn = Cbuf[nidx];                      // prefetch next step
        float vn = __bfloat162float(Vbuf[nidx]);
        float a = s + c;
        float m = fmaxf(a, v);
        s = m + log1pf(expf(-fabsf(a - v)));
        Vbuf[idx] = __float2bfloat16(expf(fminf(s, 88.0f)));
        idx = nidx; c = cn; v = vn;
    }
}

// ---------------------------------------------------------------------------
extern "C" void kernel_launch(void* const* d_in, const int* in_sizes, int n_in,
                              void* d_out, int out_size, void* d_ws, size_t ws_size,
                              hipStream_t stream)
{
    const float* x   = (const float*)d_in[0];
    const float* h0  = (const float*)d_in[1];
    const float* Wz  = (const float*)d_in[2];
    const float* bz  = (const float*)d_in[3];
    const float* Wh  = (const float*)d_in[4];
    const float* bh  = (const float*)d_in[5];
    bf16*  out  = (bf16*)d_out;     // [B,T,H] bf16: log_values, then exp(log_h)
    float* Cbuf = (float*)d_ws;     // [M,H] fp32: lc0, then scaled log_coeffs

    dim3 g1(M_ / BM, H_ / BN);      // 256 x 16
    gemm_kq<<<g1, 256, 0, stream>>>(x, Wz, bz, Wh, bh, Cbuf, out);
    groupnorm_c<<<M_, 256, 0, stream>>>(Cbuf);
    scan_seq<<<(B_ * H_) / 256, 256, 0, stream>>>(Cbuf, out, h0);
}

// Round 4
// 605.865 us; speedup vs baseline: 3.2970x; 3.2970x over previous
//
#include <hip/hip_runtime.h>
#include <hip/hip_bf16.h>
#include <math.h>

#define B_   8
#define T_   2048
#define DIN  1024
#define H_   1024
#define G_   16
#define M_   (B_ * T_)   // 16384
#define NCH  (B_ * H_)   // 8192 channels
#define SUB  32          // timesteps per scan subchunk
#define NSUB (T_ / SUB)  // 64 subchunks per channel

typedef __bf16 bf16_t;
typedef __bf16 bf16x8 __attribute__((ext_vector_type(8)));
typedef float  f32x4  __attribute__((ext_vector_type(4)));

__device__ __forceinline__ float bf2f(unsigned short u) {
    union { unsigned int i; float f; } c; c.i = ((unsigned int)u) << 16; return c.f;
}
__device__ __forceinline__ unsigned short f2bf(float f) {
    union { __bf16 h; unsigned short u; } c; c.h = (__bf16)f; return c.u;
}
__device__ __forceinline__ float log_g_dev(float x) {
    // x>=0 : log(x+0.5) ; x<0 : x - log1p(exp(x))
    return (x >= 0.f) ? logf(x + 0.5f) : (x - log1pf(expf(x)));
}
// logaddexp via hardware exp2/log2 (v_exp_f32 / v_log_f32)
__device__ __forceinline__ float logaddexp_f(float a, float b) {
    float m = fmaxf(a, b);
    float d = -fabsf(a - b);                 // <= 0 (or -inf)
    return m + 0.69314718056f * log2f(1.f + exp2f(d * 1.44269504089f));
}

// ---------------------------------------------------------------------------
// bf16 MFMA GEMM, 128x128 tile, BK=32, fused pointwise epilogue.
//   k = x@Wz^T + bz ; q = x@Wh^T + bh
//   Cb = -softplus(k)  (bf16, ws) ; Vb = -softplus(-k) + log_g(q) (bf16, out)
// LDS layout (swizzled, conflict-free): for tile row r (r = mt*16+m) and
// k-quad q (8 bf16), slot index16 = (mt*4+q)*16 + m -> lane L of wave reading
// m-tile mt gets its fragment at index16 = mt*64 + L (fully sequential).
// ---------------------------------------------------------------------------
#define BM 128
#define BN 128
#define BK 32

__global__ __launch_bounds__(256) void gemm_mfma(
    const float* __restrict__ X,
    const float* __restrict__ Wz, const float* __restrict__ bz,
    const float* __restrict__ Wh, const float* __restrict__ bh,
    bf16_t* __restrict__ Cb, bf16_t* __restrict__ Vb)
{
    __shared__ bf16_t sA[BM * BK];
    __shared__ bf16_t sZ[BN * BK];
    __shared__ bf16_t sH[BN * BK];

    const int tid = threadIdx.x;
    const int m0 = blockIdx.x * BM;
    const int n0 = blockIdx.y * BN;

    // staging: thread t loads 16 consecutive fp32 of row r, k-half kh
    const int r    = tid >> 1;            // 0..127
    const int kh   = (tid & 1) << 4;      // 0 or 16
    const int mt_s = r >> 4, mm_s = r & 15;
    const int q0   = (tid & 1) * 2;       // first k-quad of this half
    const int lds0 = ((mt_s * 4 + q0) * 16 + mm_s) * 8;   // element offset

    const float* Xg = X  + (size_t)(m0 + r) * DIN + kh;
    const float* Zg = Wz + (size_t)(n0 + r) * DIN + kh;
    const float* Hg = Wh + (size_t)(n0 + r) * DIN + kh;

    const int lane = tid & 63;
    const int wave = tid >> 6;
    const int wm = wave & 1, wn = wave >> 1;   // 2x2 wave grid, 64x64 each

    f32x4 dz[4][4], dh[4][4];
    #pragma unroll
    for (int i = 0; i < 4; ++i)
        #pragma unroll
        for (int j = 0; j < 4; ++j) { dz[i][j] = (f32x4)0.f; dh[i][j] = (f32x4)0.f; }

    for (int k0 = 0; k0 < DIN; k0 += BK) {
        float4 x0 = *(const float4*)(Xg + k0);
        float4 x1 = *(const float4*)(Xg + k0 + 4);
        float4 x2 = *(const float4*)(Xg + k0 + 8);
        float4 x3 = *(const float4*)(Xg + k0 + 12);
        float4 z0 = *(const float4*)(Zg + k0);
        float4 z1 = *(const float4*)(Zg + k0 + 4);
        float4 z2 = *(const float4*)(Zg + k0 + 8);
        float4 z3 = *(const float4*)(Zg + k0 + 12);
        float4 h0v = *(const float4*)(Hg + k0);
        float4 h1 = *(const float4*)(Hg + k0 + 4);
        float4 h2 = *(const float4*)(Hg + k0 + 8);
        float4 h3 = *(const float4*)(Hg + k0 + 12);

        __syncthreads();   // previous iteration's LDS reads done

        bf16x8 p, s;
        p = (bf16x8){(__bf16)x0.x,(__bf16)x0.y,(__bf16)x0.z,(__bf16)x0.w,
                     (__bf16)x1.x,(__bf16)x1.y,(__bf16)x1.z,(__bf16)x1.w};
        s = (bf16x8){(__bf16)x2.x,(__bf16)x2.y,(__bf16)x2.z,(__bf16)x2.w,
                     (__bf16)x3.x,(__bf16)x3.y,(__bf16)x3.z,(__bf16)x3.w};
        *(bf16x8*)(sA + lds0) = p;  *(bf16x8*)(sA + lds0 + 128) = s;
        p = (bf16x8){(__bf16)z0.x,(__bf16)z0.y,(__bf16)z0.z,(__bf16)z0.w,
                     (__bf16)z1.x,(__bf16)z1.y,(__bf16)z1.z,(__bf16)z1.w};
        s = (bf16x8){(__bf16)z2.x,(__bf16)z2.y,(__bf16)z2.z,(__bf16)z2.w,
                     (__bf16)z3.x,(__bf16)z3.y,(__bf16)z3.z,(__bf16)z3.w};
        *(bf16x8*)(sZ + lds0) = p;  *(bf16x8*)(sZ + lds0 + 128) = s;
        p = (bf16x8){(__bf16)h0v.x,(__bf16)h0v.y,(__bf16)h0v.z,(__bf16)h0v.w,
                     (__bf16)h1.x,(__bf16)h1.y,(__bf16)h1.z,(__bf16)h1.w};
        s = (bf16x8){(__bf16)h2.x,(__bf16)h2.y,(__bf16)h2.z,(__bf16)h2.w,
                     (__bf16)h3.x,(__bf16)h3.y,(__bf16)h3.z,(__bf16)h3.w};
        *(bf16x8*)(sH + lds0) = p;  *(bf16x8*)(sH + lds0 + 128) = s;

        __syncthreads();

        bf16x8 af[4], bzf[4], bhf[4];
        #pragma unroll
        for (int i = 0; i < 4; ++i)
            af[i] = *(bf16x8*)(sA + ((wm * 4 + i) * 64 + lane) * 8);
        #pragma unroll
        for (int j = 0; j < 4; ++j) {
            bzf[j] = *(bf16x8*)(sZ + ((wn * 4 + j) * 64 + lane) * 8);
            bhf[j] = *(bf16x8*)(sH + ((wn * 4 + j) * 64 + lane) * 8);
        }
        #pragma unroll
        for (int i = 0; i < 4; ++i)
            #pragma unroll
            for (int j = 0; j < 4; ++j) {
                dz[i][j] = __builtin_amdgcn_mfma_f32_16x16x32_bf16(af[i], bzf[j], dz[i][j], 0, 0, 0);
                dh[i][j] = __builtin_amdgcn_mfma_f32_16x16x32_bf16(af[i], bhf[j], dh[i][j], 0, 0, 0);
            }
    }

    // epilogue: D layout col = lane&15, row = (lane>>4)*4 + reg
    const int cq = lane >> 4;
    const int cn = lane & 15;
    #pragma unroll
    for (int j = 0; j < 4; ++j) {
        const int col = n0 + (wn * 4 + j) * 16 + cn;
        const float bzv = bz[col];
        const float bhv = bh[col];
        #pragma unroll
        for (int i = 0; i < 4; ++i) {
            const int row0 = m0 + (wm * 4 + i) * 16 + cq * 4;
            #pragma unroll
            for (int rr = 0; rr < 4; ++rr) {
                float k = dz[i][j][rr] + bzv;
                float q = dh[i][j][rr] + bhv;
                float t   = log1pf(expf(-fabsf(k)));
                float lz  = fminf(k, 0.f) - t;
                float lc0 = -fmaxf(k, 0.f) - t;
                size_t off = (size_t)(row0 + rr) * H_ + col;
                ((unsigned short*)Cb)[off] = f2bf(lc0);
                ((unsigned short*)Vb)[off] = f2bf(lz + log_g_dev(q));
            }
        }
    }
}

// ---------------------------------------------------------------------------
// Group-norm over C (bf16). One block per (b,t) row of 1024 channels.
// ---------------------------------------------------------------------------
__global__ __launch_bounds__(256) void groupnorm_c(bf16_t* __restrict__ Cb)
{
    __shared__ float snorm[G_];
    __shared__ float s_lse;

    const int row = blockIdx.x;
    const int tid = threadIdx.x;            // 4 channels each
    const size_t base = (size_t)row * H_ + (tid << 2);

    ushort4 u = *(ushort4*)((unsigned short*)Cb + base);
    float cc[4] = {bf2f(u.x), bf2f(u.y), bf2f(u.z), bf2f(u.w)};

    float ss = cc[0]*cc[0] + cc[1]*cc[1] + cc[2]*cc[2] + cc[3]*cc[3];
    ss += __shfl_xor(ss, 1);
    ss += __shfl_xor(ss, 2);
    ss += __shfl_xor(ss, 4);
    ss += __shfl_xor(ss, 8);
    const float nrm = sqrtf(ss);
    if ((tid & 15) == 0) snorm[tid >> 4] = nrm;
    __syncthreads();
    if (tid == 0) {
        float mx = snorm[0];
        #pragma unroll
        for (int g = 1; g < G_; ++g) mx = fmaxf(mx, snorm[g]);
        float se = 0.f;
        #pragma unroll
        for (int g = 0; g < G_; ++g) se += expf(snorm[g] - mx);
        s_lse = mx + logf(se);
    }
    __syncthreads();
    const float fac = (nrm - s_lse) / nrm;

    ushort4 o = { f2bf(cc[0]*fac), f2bf(cc[1]*fac), f2bf(cc[2]*fac), f2bf(cc[3]*fac) };
    *(ushort4*)((unsigned short*)Cb + base) = o;
}

// ---------------------------------------------------------------------------
// Chunked parallel scan, 3 phases.
// Subchunk summary: A = sum(c), B = local scan from -inf:
//   s_out = logaddexp(s_in + A, B)
// ---------------------------------------------------------------------------
__global__ __launch_bounds__(256) void scan_sum(
    const bf16_t* __restrict__ Cb, const bf16_t* __restrict__ Vb,
    float2* __restrict__ Sb)
{
    const int hl   = threadIdx.x & 63;
    const int ssub = threadIdx.x >> 6;                  // 0..3
    const int ch   = blockIdx.x * 64 + hl;              // 0..8191
    const int subg = blockIdx.y * 4 + ssub;             // 0..63
    const int b = ch >> 10, h = ch & 1023;

    size_t idx = ((size_t)b * T_ + (size_t)subg * SUB) * H_ + h;
    float A = 0.f, Bv = -INFINITY;
    #pragma unroll 4
    for (int s = 0; s < SUB; ++s) {
        float c = bf2f(((const unsigned short*)Cb)[idx]);
        float v = bf2f(((const unsigned short*)Vb)[idx]);
        A += c;
        Bv = logaddexp_f(Bv + c, v);
        idx += H_;
    }
    float2 o; o.x = A; o.y = Bv;
    Sb[(size_t)subg * NCH + ch] = o;
}

__global__ __launch_bounds__(256) void scan_mid(
    float2* __restrict__ Sb, const float* __restrict__ h0)
{
    const int ch = blockIdx.x * 256 + threadIdx.x;      // 0..8191
    float s = log_g_dev(h0[ch]);
    for (int k = 0; k < NSUB; ++k) {
        float2 ab = Sb[(size_t)k * NCH + ch];
        float snew = logaddexp_f(s + ab.x, ab.y);
        Sb[(size_t)k * NCH + ch].x = s;    // seed (incoming state) for subchunk k
        s = snew;
    }
}

__global__ __launch_bounds__(256) void scan_out(
    const bf16_t* __restrict__ Cb, bf16_t* Vb /* == d_out */,
    const float2* __restrict__ Sb)
{
    const int hl   = threadIdx.x & 63;
    const int ssub = threadIdx.x >> 6;
    const int ch   = blockIdx.x * 64 + hl;
    const int subg = blockIdx.y * 4 + ssub;
    const int b = ch >> 10, h = ch & 1023;

    float s = Sb[(size_t)subg * NCH + ch].x;
    size_t idx = ((size_t)b * T_ + (size_t)subg * SUB) * H_ + h;
    #pragma unroll 4
    for (int t = 0; t < SUB; ++t) {
        float c = bf2f(((const unsigned short*)Cb)[idx]);
        float v = bf2f(((const unsigned short*)Vb)[idx]);
        s = logaddexp_f(s + c, v);
        float out = exp2f(fminf(s, 88.f) * 1.44269504089f);  // finite, <= 1.7e38
        ((unsigned short*)Vb)[idx] = f2bf(out);
        idx += H_;
    }
}

// ---------------------------------------------------------------------------
extern "C" void kernel_launch(void* const* d_in, const int* in_sizes, int n_in,
                              void* d_out, int out_size, void* d_ws, size_t ws_size,
                              hipStream_t stream)
{
    const float* x   = (const float*)d_in[0];
    const float* h0  = (const float*)d_in[1];
    const float* Wz  = (const float*)d_in[2];
    const float* bz  = (const float*)d_in[3];
    const float* Wh  = (const float*)d_in[4];
    const float* bh  = (const float*)d_in[5];

    bf16_t* out = (bf16_t*)d_out;                        // [B,T,H] bf16
    bf16_t* Cb  = (bf16_t*)d_ws;                         // 33.5 MB bf16 log_coeffs
    float2* Sb  = (float2*)((char*)d_ws + (size_t)M_ * H_ * 2);  // 4 MB summaries

    gemm_mfma<<<dim3(M_ / BM, H_ / BN), 256, 0, stream>>>(x, Wz, bz, Wh, bh, Cb, out);
    groupnorm_c<<<M_, 256, 0, stream>>>(Cb);
    scan_sum<<<dim3(NCH / 64, NSUB / 4), 256, 0, stream>>>(Cb, out, Sb);
    scan_mid<<<NCH / 256, 256, 0, stream>>>(Sb, h0);
    scan_out<<<dim3(NCH / 64, NSUB / 4), 256, 0, stream>>>(Cb, out, Sb);
}

// Round 5
// 373.488 us; speedup vs baseline: 5.3483x; 1.6222x over previous
//
#include <hip/hip_runtime.h>
#include <hip/hip_bf16.h>
#include <math.h>

#define B_   8
#define T_   2048
#define DIN  1024
#define H_   1024
#define G_   16
#define M_   (B_ * T_)   // 16384
#define NCH  (B_ * H_)   // 8192 channels
#define SUB  32          // timesteps per scan subchunk
#define NSUB (T_ / SUB)  // 64 subchunks per channel

#define LN2f     0.69314718056f
#define LOG2Ef   1.44269504089f

typedef __bf16 bf16_t;
typedef __bf16 bf16x8 __attribute__((ext_vector_type(8)));
typedef float  f32x4  __attribute__((ext_vector_type(4)));

__device__ __forceinline__ float bf2f(unsigned short u) {
    union { unsigned int i; float f; } c; c.i = ((unsigned int)u) << 16; return c.f;
}
__device__ __forceinline__ unsigned short f2bf(float f) {
    union { __bf16 h; unsigned short u; } c; c.h = (__bf16)f; return c.u;
}
// hardware transcendentals: v_exp_f32 (2^x), v_log_f32 (log2 x)
__device__ __forceinline__ float fexp2(float x) { return __builtin_amdgcn_exp2f(x); }
__device__ __forceinline__ float flog2(float x) { return __builtin_amdgcn_logf(x); }

__device__ __forceinline__ float log_g_dev(float x) {
    // x>=0 : log(x+0.5) ; x<0 : x - log1p(exp(x))
    return (x >= 0.f) ? LN2f * flog2(x + 0.5f)
                      : (x - LN2f * flog2(1.f + fexp2(x * LOG2Ef)));
}
__device__ __forceinline__ float logaddexp_f(float a, float b) {
    float m = fmaxf(a, b);
    float d = -fabsf(a - b);                 // <= 0 (or -inf)
    return m + LN2f * flog2(1.f + fexp2(d * LOG2Ef));
}

// async global->LDS, 16 bytes per lane; LDS dest = uniform base + lane*16
__device__ __forceinline__ void async16(bf16_t* lds, const bf16_t* g) {
    __builtin_amdgcn_global_load_lds(
        (const __attribute__((address_space(1))) void*)g,
        (__attribute__((address_space(3))) void*)lds, 16, 0, 0);
}

// ---------------------------------------------------------------------------
// fp32 -> bf16 bulk convert (8 elems/thread)
// ---------------------------------------------------------------------------
__global__ __launch_bounds__(256) void cvt_bf16(
    const float* __restrict__ src, bf16_t* __restrict__ dst, int n8)
{
    int i = blockIdx.x * 256 + threadIdx.x;
    if (i >= n8) return;
    float4 a = ((const float4*)src)[2 * i];
    float4 b = ((const float4*)src)[2 * i + 1];
    bf16x8 o = {(__bf16)a.x, (__bf16)a.y, (__bf16)a.z, (__bf16)a.w,
                (__bf16)b.x, (__bf16)b.y, (__bf16)b.z, (__bf16)b.w};
    ((bf16x8*)dst)[i] = o;
}

// ---------------------------------------------------------------------------
// bf16 MFMA GEMM (m97-style staging), 128x128 tile, BK=32, fused epilogue.
//   k = x@Wz^T + bz ; q = x@Wh^T + bh
//   Cb = -softplus(k) (bf16, ws) ; Vb = -softplus(-k) + log_g(q) (bf16, out)
// LDS layout: chunk c (16B) = (mt*64 + L) holds row mt*16+(L&15),
// k-quad L>>4 -> A-fragment read for m-tile mt at lane L is LDS[(mt*64+L)*16B]
// (contiguous per wave, conflict-free; matches global_load_lds lane mapping).
// ---------------------------------------------------------------------------
#define BM 128
#define BN 128
#define BK 32

__global__ __launch_bounds__(256) void gemm_mfma(
    const bf16_t* __restrict__ Xb,
    const bf16_t* __restrict__ Wzb, const float* __restrict__ bz,
    const bf16_t* __restrict__ Whb, const float* __restrict__ bh,
    bf16_t* __restrict__ Cb, bf16_t* __restrict__ Vb)
{
    __shared__ bf16_t sA[BM * BK];   // 8 KB
    __shared__ bf16_t sZ[BN * BK];
    __shared__ bf16_t sH[BN * BK];

    const int tid  = threadIdx.x;
    const int m0   = blockIdx.x * BM;
    const int n0   = blockIdx.y * BN;
    const int lane = tid & 63;
    const int wave = tid >> 6;
    const int wm = wave & 1, wn = wave >> 1;   // 2x2 wave grid, 64x64 each

    // staging addresses: wave stages m-tiles mt = wave*2, wave*2+1 per matrix
    const int srow = lane & 15;
    const int scol = (lane >> 4) * 8;
    const size_t gA0 = (size_t)(m0 + wave * 32      + srow) * DIN + scol;
    const size_t gA1 = (size_t)(m0 + wave * 32 + 16 + srow) * DIN + scol;
    const size_t gB0 = (size_t)(n0 + wave * 32      + srow) * DIN + scol;
    const size_t gB1 = (size_t)(n0 + wave * 32 + 16 + srow) * DIN + scol;
    bf16_t* lA0 = sA + (wave * 2    ) * 512;   // 512 bf16 = 1 KB per instr
    bf16_t* lA1 = sA + (wave * 2 + 1) * 512;
    bf16_t* lZ0 = sZ + (wave * 2    ) * 512;
    bf16_t* lZ1 = sZ + (wave * 2 + 1) * 512;
    bf16_t* lH0 = sH + (wave * 2    ) * 512;
    bf16_t* lH1 = sH + (wave * 2 + 1) * 512;

    f32x4 dz[4][4], dh[4][4];
    #pragma unroll
    for (int i = 0; i < 4; ++i)
        #pragma unroll
        for (int j = 0; j < 4; ++j) { dz[i][j] = (f32x4)0.f; dh[i][j] = (f32x4)0.f; }

    for (int k0 = 0; k0 < DIN; k0 += BK) {
        __syncthreads();                         // compute on prev tile done
        async16(lA0, Xb  + gA0 + k0);
        async16(lA1, Xb  + gA1 + k0);
        async16(lZ0, Wzb + gB0 + k0);
        async16(lZ1, Wzb + gB1 + k0);
        async16(lH0, Whb + gB0 + k0);
        async16(lH1, Whb + gB1 + k0);
        __syncthreads();                         // vmcnt(0) drain + barrier

        bf16x8 af[4], bzf[4], bhf[4];
        #pragma unroll
        for (int i = 0; i < 4; ++i)
            af[i] = *(bf16x8*)(sA + ((wm * 4 + i) * 64 + lane) * 8);
        #pragma unroll
        for (int j = 0; j < 4; ++j) {
            bzf[j] = *(bf16x8*)(sZ + ((wn * 4 + j) * 64 + lane) * 8);
            bhf[j] = *(bf16x8*)(sH + ((wn * 4 + j) * 64 + lane) * 8);
        }
        #pragma unroll
        for (int i = 0; i < 4; ++i)
            #pragma unroll
            for (int j = 0; j < 4; ++j) {
                dz[i][j] = __builtin_amdgcn_mfma_f32_16x16x32_bf16(af[i], bzf[j], dz[i][j], 0, 0, 0);
                dh[i][j] = __builtin_amdgcn_mfma_f32_16x16x32_bf16(af[i], bhf[j], dh[i][j], 0, 0, 0);
            }
    }

    // epilogue: D layout col = lane&15, row = (lane>>4)*4 + reg
    const int cq = lane >> 4;
    const int cn = lane & 15;
    #pragma unroll
    for (int j = 0; j < 4; ++j) {
        const int col = n0 + (wn * 4 + j) * 16 + cn;
        const float bzv = bz[col];
        const float bhv = bh[col];
        #pragma unroll
        for (int i = 0; i < 4; ++i) {
            const int row0 = m0 + (wm * 4 + i) * 16 + cq * 4;
            #pragma unroll
            for (int rr = 0; rr < 4; ++rr) {
                float k = dz[i][j][rr] + bzv;
                float q = dh[i][j][rr] + bhv;
                float t   = LN2f * flog2(1.f + fexp2(-fabsf(k) * LOG2Ef));
                float lz  = fminf(k, 0.f) - t;
                float lc0 = -fmaxf(k, 0.f) - t;
                size_t off = (size_t)(row0 + rr) * H_ + col;
                ((unsigned short*)Cb)[off] = f2bf(lc0);
                ((unsigned short*)Vb)[off] = f2bf(lz + log_g_dev(q));
            }
        }
    }
}

// ---------------------------------------------------------------------------
// Group-norm over C (bf16). One block per (b,t) row of 1024 channels.
// ---------------------------------------------------------------------------
__global__ __launch_bounds__(256) void groupnorm_c(bf16_t* __restrict__ Cb)
{
    __shared__ float snorm[G_];
    __shared__ float s_lse;

    const int row = blockIdx.x;
    const int tid = threadIdx.x;            // 4 channels each
    const size_t base = (size_t)row * H_ + (tid << 2);

    ushort4 u = *(ushort4*)((unsigned short*)Cb + base);
    float cc[4] = {bf2f(u.x), bf2f(u.y), bf2f(u.z), bf2f(u.w)};

    float ss = cc[0]*cc[0] + cc[1]*cc[1] + cc[2]*cc[2] + cc[3]*cc[3];
    ss += __shfl_xor(ss, 1);
    ss += __shfl_xor(ss, 2);
    ss += __shfl_xor(ss, 4);
    ss += __shfl_xor(ss, 8);
    const float nrm = sqrtf(ss);
    if ((tid & 15) == 0) snorm[tid >> 4] = nrm;
    __syncthreads();
    if (tid == 0) {
        float mx = snorm[0];
        #pragma unroll
        for (int g = 1; g < G_; ++g) mx = fmaxf(mx, snorm[g]);
        float se = 0.f;
        #pragma unroll
        for (int g = 0; g < G_; ++g) se += fexp2((snorm[g] - mx) * LOG2Ef);
        s_lse = mx + LN2f * flog2(se);
    }
    __syncthreads();
    const float fac = (nrm - s_lse) / nrm;

    ushort4 o = { f2bf(cc[0]*fac), f2bf(cc[1]*fac), f2bf(cc[2]*fac), f2bf(cc[3]*fac) };
    *(ushort4*)((unsigned short*)Cb + base) = o;
}

// ---------------------------------------------------------------------------
// Chunked parallel scan, 3 phases.
//   subchunk summary: A = sum(c), B = local scan from -inf
//   composition: s_out = logaddexp(s_in + A, B)
// ---------------------------------------------------------------------------
__global__ __launch_bounds__(256) void scan_sum(
    const bf16_t* __restrict__ Cb, const bf16_t* __restrict__ Vb,
    float2* __restrict__ Sb)
{
    const int hl   = threadIdx.x & 63;
    const int ssub = threadIdx.x >> 6;                  // 0..3
    const int ch   = blockIdx.x * 64 + hl;              // 0..8191
    const int subg = blockIdx.y * 4 + ssub;             // 0..63
    const int b = ch >> 10, h = ch & 1023;

    size_t idx = ((size_t)b * T_ + (size_t)subg * SUB) * H_ + h;
    float A = 0.f, Bv = -INFINITY;
    #pragma unroll 4
    for (int s = 0; s < SUB; ++s) {
        float c = bf2f(((const unsigned short*)Cb)[idx]);
        float v = bf2f(((const unsigned short*)Vb)[idx]);
        A += c;
        Bv = logaddexp_f(Bv + c, v);
        idx += H_;
    }
    float2 o; o.x = A; o.y = Bv;
    Sb[(size_t)subg * NCH + ch] = o;
}

__global__ __launch_bounds__(256) void scan_mid(
    float2* __restrict__ Sb, const float* __restrict__ h0)
{
    const int ch = blockIdx.x * 256 + threadIdx.x;      // 0..8191
    float s = log_g_dev(h0[ch]);
    for (int k = 0; k < NSUB; ++k) {
        float2 ab = Sb[(size_t)k * NCH + ch];
        float snew = logaddexp_f(s + ab.x, ab.y);
        Sb[(size_t)k * NCH + ch].x = s;    // seed (incoming state) for subchunk k
        s = snew;
    }
}

__global__ __launch_bounds__(256) void scan_out(
    const bf16_t* __restrict__ Cb, bf16_t* Vb /* == d_out */,
    const float2* __restrict__ Sb)
{
    const int hl   = threadIdx.x & 63;
    const int ssub = threadIdx.x >> 6;
    const int ch   = blockIdx.x * 64 + hl;
    const int subg = blockIdx.y * 4 + ssub;
    const int b = ch >> 10, h = ch & 1023;

    float s = Sb[(size_t)subg * NCH + ch].x;
    size_t idx = ((size_t)b * T_ + (size_t)subg * SUB) * H_ + h;
    #pragma unroll 4
    for (int t = 0; t < SUB; ++t) {
        float c = bf2f(((const unsigned short*)Cb)[idx]);
        float v = bf2f(((const unsigned short*)Vb)[idx]);
        s = logaddexp_f(s + c, v);
        float out = fexp2(fminf(s, 88.f) * LOG2Ef);  // finite, <= 1.7e38
        ((unsigned short*)Vb)[idx] = f2bf(out);
        idx += H_;
    }
}

// ---------------------------------------------------------------------------
extern "C" void kernel_launch(void* const* d_in, const int* in_sizes, int n_in,
                              void* d_out, int out_size, void* d_ws, size_t ws_size,
                              hipStream_t stream)
{
    const float* x   = (const float*)d_in[0];
    const float* h0  = (const float*)d_in[1];
    const float* Wz  = (const float*)d_in[2];
    const float* bz  = (const float*)d_in[3];
    const float* Wh  = (const float*)d_in[4];
    const float* bh  = (const float*)d_in[5];

    bf16_t* out = (bf16_t*)d_out;                                 // [B,T,H] bf16
    char*   ws  = (char*)d_ws;
    bf16_t* Cb  = (bf16_t*)ws;                                    // 33.5 MB
    float2* Sb  = (float2*)(ws + (size_t)M_ * H_ * 2);            //  4.0 MB
    bf16_t* Xb  = (bf16_t*)(ws + (size_t)M_ * H_ * 2 + (size_t)NSUB * NCH * 8);   // 33.5 MB
    bf16_t* Wzb = Xb + (size_t)M_ * DIN;                          //  2.0 MB
    bf16_t* Whb = Wzb + (size_t)H_ * DIN;                         //  2.0 MB  (total 72 MiB)

    cvt_bf16<<<(M_ * DIN / 8) / 256, 256, 0, stream>>>(x,  Xb,  M_ * DIN / 8);
    cvt_bf16<<<(H_ * DIN / 8) / 256, 256, 0, stream>>>(Wz, Wzb, H_ * DIN / 8);
    cvt_bf16<<<(H_ * DIN / 8) / 256, 256, 0, stream>>>(Wh, Whb, H_ * DIN / 8);

    gemm_mfma<<<dim3(M_ / BM, H_ / BN), 256, 0, stream>>>(Xb, Wzb, bz, Whb, bh, Cb, out);
    groupnorm_c<<<M_, 256, 0, stream>>>(Cb);
    scan_sum<<<dim3(NCH / 64, NSUB / 4), 256, 0, stream>>>(Cb, out, Sb);
    scan_mid<<<NCH / 256, 256, 0, stream>>>(Sb, h0);
    scan_out<<<dim3(NCH / 64, NSUB / 4), 256, 0, stream>>>(Cb, out, Sb);
}

// Round 6
// 312.348 us; speedup vs baseline: 6.3953x; 1.1957x over previous
//
#include <hip/hip_runtime.h>
#include <hip/hip_bf16.h>
#include <math.h>

#define B_   8
#define T_   2048
#define DIN  1024
#define H_   1024
#define G_   16
#define M_   (B_ * T_)   // 16384
#define NCH  (B_ * H_)   // 8192 channels
#define SUB  32          // timesteps per scan subchunk
#define NSUB (T_ / SUB)  // 64 subchunks per channel

#define LN2f     0.69314718056f
#define LOG2Ef   1.44269504089f

typedef __bf16 bf16_t;
typedef __bf16 bf16x8 __attribute__((ext_vector_type(8)));
typedef float  f32x4  __attribute__((ext_vector_type(4)));

__device__ __forceinline__ float bf2f(unsigned short u) {
    union { unsigned int i; float f; } c; c.i = ((unsigned int)u) << 16; return c.f;
}
__device__ __forceinline__ unsigned short f2bf(float f) {
    union { __bf16 h; unsigned short u; } c; c.h = (__bf16)f; return c.u;
}
// hardware transcendentals: v_exp_f32 (2^x), v_log_f32 (log2 x)
__device__ __forceinline__ float fexp2(float x) { return __builtin_amdgcn_exp2f(x); }
__device__ __forceinline__ float flog2(float x) { return __builtin_amdgcn_logf(x); }

__device__ __forceinline__ float log_g_dev(float x) {
    return (x >= 0.f) ? LN2f * flog2(x + 0.5f)
                      : (x - LN2f * flog2(1.f + fexp2(x * LOG2Ef)));
}
__device__ __forceinline__ float logaddexp_f(float a, float b) {
    float m = fmaxf(a, b);
    float d = -fabsf(a - b);                 // <= 0 (or -inf)
    return m + LN2f * flog2(1.f + fexp2(d * LOG2Ef));
}

// async global->LDS, 16 bytes per lane; LDS dest = uniform base + lane*16
__device__ __forceinline__ void async16(bf16_t* lds, const bf16_t* g) {
    __builtin_amdgcn_global_load_lds(
        (const __attribute__((address_space(1))) void*)g,
        (__attribute__((address_space(3))) void*)lds, 16, 0, 0);
}

// ---------------------------------------------------------------------------
// fp32 -> bf16 bulk convert (8 elems/thread)
// ---------------------------------------------------------------------------
__global__ __launch_bounds__(256) void cvt_bf16(
    const float* __restrict__ src, bf16_t* __restrict__ dst, int n8)
{
    int i = blockIdx.x * 256 + threadIdx.x;
    if (i >= n8) return;
    float4 a = ((const float4*)src)[2 * i];
    float4 b = ((const float4*)src)[2 * i + 1];
    bf16x8 o = {(__bf16)a.x, (__bf16)a.y, (__bf16)a.z, (__bf16)a.w,
                (__bf16)b.x, (__bf16)b.y, (__bf16)b.z, (__bf16)b.w};
    ((bf16x8*)dst)[i] = o;
}

// ---------------------------------------------------------------------------
// bf16 MFMA GEMM, 128x64 block tile, BK=32, wave tile 64x32 per matrix.
// acc = 64 VGPR -> 4 waves/SIMD with __launch_bounds__(256,4).
// Per wave-iter: 4 async16 (A:2, Z:1, H:1), 16 MFMA. Fused epilogue:
//   Cb = -softplus(k) (bf16, ws) ; Vb = -softplus(-k) + log_g(q) (bf16, out)
// LDS chunk layout: 16B chunk (mt*64 + L) = row mt*16+(L&15), kquad L>>4.
// ---------------------------------------------------------------------------
#define BM 128
#define BN 64
#define BK 32

__global__ __launch_bounds__(256, 4) void gemm_mfma(
    const bf16_t* __restrict__ Xb,
    const bf16_t* __restrict__ Wzb, const float* __restrict__ bz,
    const bf16_t* __restrict__ Whb, const float* __restrict__ bh,
    bf16_t* __restrict__ Cb, bf16_t* __restrict__ Vb)
{
    __shared__ bf16_t sA[BM * BK];   // 8 KB
    __shared__ bf16_t sZ[BN * BK];   // 4 KB
    __shared__ bf16_t sH[BN * BK];   // 4 KB

    const int tid  = threadIdx.x;
    const int m0   = blockIdx.x * BM;
    const int n0   = blockIdx.y * BN;
    const int lane = tid & 63;
    const int wave = tid >> 6;
    const int wm = wave & 1, wn = wave >> 1;   // wave tile: rows wm*64, cols wn*32

    // staging: wave stages A m-tiles (wave*2, wave*2+1), Z/H n-tile (wave)
    const int srow = lane & 15;
    const int scol = (lane >> 4) * 8;
    const size_t gA0 = (size_t)(m0 + wave * 32      + srow) * DIN + scol;
    const size_t gA1 = (size_t)(m0 + wave * 32 + 16 + srow) * DIN + scol;
    const size_t gB0 = (size_t)(n0 + wave * 16      + srow) * DIN + scol;
    bf16_t* lA0 = sA + (wave * 2    ) * 512;
    bf16_t* lA1 = sA + (wave * 2 + 1) * 512;
    bf16_t* lZ0 = sZ + wave * 512;
    bf16_t* lH0 = sH + wave * 512;

    f32x4 dz[4][2], dh[4][2];
    #pragma unroll
    for (int i = 0; i < 4; ++i)
        #pragma unroll
        for (int j = 0; j < 2; ++j) { dz[i][j] = (f32x4)0.f; dh[i][j] = (f32x4)0.f; }

    for (int k0 = 0; k0 < DIN; k0 += BK) {
        __syncthreads();                         // compute on prev tile done
        async16(lA0, Xb  + gA0 + k0);
        async16(lA1, Xb  + gA1 + k0);
        async16(lZ0, Wzb + gB0 + k0);
        async16(lH0, Whb + gB0 + k0);
        __syncthreads();                         // vmcnt(0) drain + barrier

        bf16x8 af[4], bzf[2], bhf[2];
        #pragma unroll
        for (int i = 0; i < 4; ++i)
            af[i] = *(bf16x8*)(sA + ((wm * 4 + i) * 64 + lane) * 8);
        #pragma unroll
        for (int j = 0; j < 2; ++j) {
            bzf[j] = *(bf16x8*)(sZ + ((wn * 2 + j) * 64 + lane) * 8);
            bhf[j] = *(bf16x8*)(sH + ((wn * 2 + j) * 64 + lane) * 8);
        }
        #pragma unroll
        for (int i = 0; i < 4; ++i)
            #pragma unroll
            for (int j = 0; j < 2; ++j) {
                dz[i][j] = __builtin_amdgcn_mfma_f32_16x16x32_bf16(af[i], bzf[j], dz[i][j], 0, 0, 0);
                dh[i][j] = __builtin_amdgcn_mfma_f32_16x16x32_bf16(af[i], bhf[j], dh[i][j], 0, 0, 0);
            }
    }

    // epilogue: D layout col = lane&15, row = (lane>>4)*4 + reg
    const int cq = lane >> 4;
    const int cn = lane & 15;
    #pragma unroll
    for (int j = 0; j < 2; ++j) {
        const int col = n0 + (wn * 2 + j) * 16 + cn;
        const float bzv = bz[col];
        const float bhv = bh[col];
        #pragma unroll
        for (int i = 0; i < 4; ++i) {
            const int row0 = m0 + (wm * 4 + i) * 16 + cq * 4;
            #pragma unroll
            for (int rr = 0; rr < 4; ++rr) {
                float k = dz[i][j][rr] + bzv;
                float q = dh[i][j][rr] + bhv;
                float t   = LN2f * flog2(1.f + fexp2(-fabsf(k) * LOG2Ef));
                float lz  = fminf(k, 0.f) - t;
                float lc0 = -fmaxf(k, 0.f) - t;
                size_t off = (size_t)(row0 + rr) * H_ + col;
                ((unsigned short*)Cb)[off] = f2bf(lc0);
                ((unsigned short*)Vb)[off] = f2bf(lz + log_g_dev(q));
            }
        }
    }
}

// ---------------------------------------------------------------------------
// Group-norm over C (bf16). One block per (b,t) row of 1024 channels.
// ---------------------------------------------------------------------------
__global__ __launch_bounds__(256) void groupnorm_c(bf16_t* __restrict__ Cb)
{
    __shared__ float snorm[G_];
    __shared__ float s_lse;

    const int row = blockIdx.x;
    const int tid = threadIdx.x;            // 4 channels each
    const size_t base = (size_t)row * H_ + (tid << 2);

    ushort4 u = *(ushort4*)((unsigned short*)Cb + base);
    float cc[4] = {bf2f(u.x), bf2f(u.y), bf2f(u.z), bf2f(u.w)};

    float ss = cc[0]*cc[0] + cc[1]*cc[1] + cc[2]*cc[2] + cc[3]*cc[3];
    ss += __shfl_xor(ss, 1);
    ss += __shfl_xor(ss, 2);
    ss += __shfl_xor(ss, 4);
    ss += __shfl_xor(ss, 8);
    const float nrm = sqrtf(ss);
    if ((tid & 15) == 0) snorm[tid >> 4] = nrm;
    __syncthreads();
    if (tid == 0) {
        float mx = snorm[0];
        #pragma unroll
        for (int g = 1; g < G_; ++g) mx = fmaxf(mx, snorm[g]);
        float se = 0.f;
        #pragma unroll
        for (int g = 0; g < G_; ++g) se += fexp2((snorm[g] - mx) * LOG2Ef);
        s_lse = mx + LN2f * flog2(se);
    }
    __syncthreads();
    const float fac = (nrm - s_lse) / nrm;

    ushort4 o = { f2bf(cc[0]*fac), f2bf(cc[1]*fac), f2bf(cc[2]*fac), f2bf(cc[3]*fac) };
    *(ushort4*)((unsigned short*)Cb + base) = o;
}

// ---------------------------------------------------------------------------
// Chunked parallel scan, 3 phases.
//   subchunk summary: A = sum(c), B = local scan from -inf
//   composition: s_out = logaddexp(s_in + A, B)
// ---------------------------------------------------------------------------
__global__ __launch_bounds__(256) void scan_sum(
    const bf16_t* __restrict__ Cb, const bf16_t* __restrict__ Vb,
    float2* __restrict__ Sb)
{
    const int hl   = threadIdx.x & 63;
    const int ssub = threadIdx.x >> 6;                  // 0..3
    const int ch   = blockIdx.x * 64 + hl;              // 0..8191
    const int subg = blockIdx.y * 4 + ssub;             // 0..63
    const int b = ch >> 10, h = ch & 1023;

    size_t idx = ((size_t)b * T_ + (size_t)subg * SUB) * H_ + h;
    float A = 0.f, Bv = -INFINITY;
    #pragma unroll 4
    for (int s = 0; s < SUB; ++s) {
        float c = bf2f(((const unsigned short*)Cb)[idx]);
        float v = bf2f(((const unsigned short*)Vb)[idx]);
        A += c;
        Bv = logaddexp_f(Bv + c, v);
        idx += H_;
    }
    float2 o; o.x = A; o.y = Bv;
    Sb[(size_t)subg * NCH + ch] = o;
}

__global__ __launch_bounds__(256) void scan_mid(
    float2* __restrict__ Sb, const float* __restrict__ h0)
{
    const int ch = blockIdx.x * 256 + threadIdx.x;      // 0..8191
    float s = log_g_dev(h0[ch]);
    for (int k = 0; k < NSUB; ++k) {
        float2 ab = Sb[(size_t)k * NCH + ch];
        float snew = logaddexp_f(s + ab.x, ab.y);
        Sb[(size_t)k * NCH + ch].x = s;    // seed (incoming state) for subchunk k
        s = snew;
    }
}

__global__ __launch_bounds__(256) void scan_out(
    const bf16_t* __restrict__ Cb, bf16_t* Vb /* == d_out */,
    const float2* __restrict__ Sb)
{
    const int hl   = threadIdx.x & 63;
    const int ssub = threadIdx.x >> 6;
    const int ch   = blockIdx.x * 64 + hl;
    const int subg = blockIdx.y * 4 + ssub;
    const int b = ch >> 10, h = ch & 1023;

    float s = Sb[(size_t)subg * NCH + ch].x;
    size_t idx = ((size_t)b * T_ + (size_t)subg * SUB) * H_ + h;
    #pragma unroll 4
    for (int t = 0; t < SUB; ++t) {
        float c = bf2f(((const unsigned short*)Cb)[idx]);
        float v = bf2f(((const unsigned short*)Vb)[idx]);
        s = logaddexp_f(s + c, v);
        float out = fexp2(fminf(s, 88.f) * LOG2Ef);  // finite, <= 1.7e38
        ((unsigned short*)Vb)[idx] = f2bf(out);
        idx += H_;
    }
}

// ---------------------------------------------------------------------------
extern "C" void kernel_launch(void* const* d_in, const int* in_sizes, int n_in,
                              void* d_out, int out_size, void* d_ws, size_t ws_size,
                              hipStream_t stream)
{
    const float* x   = (const float*)d_in[0];
    const float* h0  = (const float*)d_in[1];
    const float* Wz  = (const float*)d_in[2];
    const float* bz  = (const float*)d_in[3];
    const float* Wh  = (const float*)d_in[4];
    const float* bh  = (const float*)d_in[5];

    bf16_t* out = (bf16_t*)d_out;                                 // [B,T,H] bf16
    char*   ws  = (char*)d_ws;
    bf16_t* Cb  = (bf16_t*)ws;                                    // 33.5 MB
    float2* Sb  = (float2*)(ws + (size_t)M_ * H_ * 2);            //  4.0 MB
    bf16_t* Xb  = (bf16_t*)(ws + (size_t)M_ * H_ * 2 + (size_t)NSUB * NCH * 8);   // 33.5 MB
    bf16_t* Wzb = Xb + (size_t)M_ * DIN;                          //  2.0 MB
    bf16_t* Whb = Wzb + (size_t)H_ * DIN;                         //  2.0 MB  (total 72 MiB)

    cvt_bf16<<<(M_ * DIN / 8) / 256, 256, 0, stream>>>(x,  Xb,  M_ * DIN / 8);
    cvt_bf16<<<(H_ * DIN / 8) / 256, 256, 0, stream>>>(Wz, Wzb, H_ * DIN / 8);
    cvt_bf16<<<(H_ * DIN / 8) / 256, 256, 0, stream>>>(Wh, Whb, H_ * DIN / 8);

    gemm_mfma<<<dim3(M_ / BM, H_ / BN), 256, 0, stream>>>(Xb, Wzb, bz, Whb, bh, Cb, out);
    groupnorm_c<<<M_, 256, 0, stream>>>(Cb);
    scan_sum<<<dim3(NCH / 64, NSUB / 4), 256, 0, stream>>>(Cb, out, Sb);
    scan_mid<<<NCH / 256, 256, 0, stream>>>(Sb, h0);
    scan_out<<<dim3(NCH / 64, NSUB / 4), 256, 0, stream>>>(Cb, out, Sb);
}